// Round 10
// baseline (4612.253 us; speedup 1.0000x reference)
//
#include <hip/hip_runtime.h>

// Problem dims (fixed)
#define Bn 64
#define Tn 512
#define En 1024
#define Hn 1024
#define Vn 50257
#define CHUNK 64
#define NCHUNK (Tn / CHUNK)
#define AGENT __HIP_MEMORY_SCOPE_AGENT

typedef __attribute__((ext_vector_type(8))) short short8;
typedef __attribute__((ext_vector_type(4))) float f32x4;
typedef __attribute__((ext_vector_type(4))) unsigned int u32x4;

__device__ __forceinline__ unsigned short f2bf(float f) {
    union { float f; unsigned u; } x; x.f = f;
    unsigned r = x.u + 0x7FFFu + ((x.u >> 16) & 1u);   // RNE; values are tame
    return (unsigned short)(r >> 16);
}
__device__ __forceinline__ float bf2f(unsigned short u) {
    union { unsigned u; float f; } x; x.u = ((unsigned)u) << 16; return x.f;
}
__device__ __forceinline__ float sigm(float x) { return 1.0f / (1.0f + __expf(-x)); }
__device__ __forceinline__ float tanh_fast(float x) {
    float e = __expf(2.0f * x);
    return (e - 1.0f) / (e + 1.0f);
}

// 16B IC-coherent load, runtime address (bypasses L1/L2 -> Infinity Cache)
#define LDHA(dst, addr)                                                      \
    asm volatile("global_load_dwordx4 %0, %1, off sc0 sc1"                   \
                 : "=v"(dst) : "v"(addr) : "memory")
// full drain + scheduler fence (rule #18: consumers must not hoist past)
#define VMW0 do { asm volatile("s_waitcnt vmcnt(0)" ::: "memory");           \
                  __builtin_amdgcn_sched_barrier(0); } while (0)

// ---------------- fp32 -> bf16 weight convert ----------------
__global__ __launch_bounds__(256)
void cvt_f32_bf16(const float* __restrict__ src, unsigned short* __restrict__ dst, int n4) {
    int i = blockIdx.x * 256 + threadIdx.x;
    if (i < n4) {
        float4 v = reinterpret_cast<const float4*>(src)[i];
        ushort4 o;
        o.x = f2bf(v.x); o.y = f2bf(v.y); o.z = f2bf(v.z); o.w = f2bf(v.w);
        reinterpret_cast<ushort4*>(dst)[i] = o;
    }
}

// ---------------- embedding gather for one 64-step chunk ----------------
__global__ __launch_bounds__(256)
void gather_x(const int* __restrict__ tokens, const float* __restrict__ emb,
              unsigned short* __restrict__ X, int t0) {
    const int r = blockIdx.x;
    const int trel = r >> 6, b = r & 63;
    const int tok = tokens[b * Tn + t0 + trel];
    const float* src = emb + (size_t)tok * En;
    const int k = threadIdx.x * 4;
    float4 v = *reinterpret_cast<const float4*>(src + k);
    ushort4 o;
    o.x = f2bf(v.x); o.y = f2bf(v.y); o.z = f2bf(v.z); o.w = f2bf(v.w);
    *reinterpret_cast<ushort4*>(X + (size_t)r * En + k) = o;
}

// ---- gemm tile body: one 128x128 tile of X @ Wih^T, output TRANSPOSED bf16:
//      G2[s][col 4096][row 64], addr = s*262144 + col*64 + (grow & 63)
__device__ __forceinline__ void gemm_tile(
    const unsigned short* __restrict__ X, const unsigned short* __restrict__ Wih,
    unsigned short* __restrict__ G2, int bx, int by,
    unsigned short (*As)[72], unsigned short (*Bs)[72], int tid)
{
    const int w = tid >> 6, l = tid & 63;
    const int wr = w >> 1, wc = w & 1;
    const int koff = (l >> 4) * 8;

    f32x4 acc[4][4];
#pragma unroll
    for (int i = 0; i < 4; ++i)
#pragma unroll
        for (int j = 0; j < 4; ++j) acc[i][j] = (f32x4){0.f, 0.f, 0.f, 0.f};

    for (int kk = 0; kk < En / 64; ++kk) {
        __syncthreads();
#pragma unroll
        for (int j = 0; j < 4; ++j) {
            const int u = tid * 4 + j;
            const int row = u >> 3, ku = (u & 7) * 8;
            *reinterpret_cast<short8*>(&As[row][ku]) =
                *reinterpret_cast<const short8*>(X + (size_t)(by * 128 + row) * En + kk * 64 + ku);
            *reinterpret_cast<short8*>(&Bs[row][ku]) =
                *reinterpret_cast<const short8*>(Wih + (size_t)(bx * 128 + row) * En + kk * 64 + ku);
        }
        __syncthreads();

#pragma unroll
        for (int kc = 0; kc < 2; ++kc) {
            const int k0 = kc * 32 + koff;
            short8 af[4], bf[4];
#pragma unroll
            for (int i = 0; i < 4; ++i)
                af[i] = *reinterpret_cast<const short8*>(&As[wr * 64 + i * 16 + (l & 15)][k0]);
#pragma unroll
            for (int j = 0; j < 4; ++j)
                bf[j] = *reinterpret_cast<const short8*>(&Bs[wc * 64 + j * 16 + (l & 15)][k0]);
#pragma unroll
            for (int i = 0; i < 4; ++i)
#pragma unroll
                for (int j = 0; j < 4; ++j)
                    acc[i][j] = __builtin_amdgcn_mfma_f32_16x16x32_bf16(af[i], bf[j], acc[i][j], 0, 0, 0);
        }
    }

    const int rr = 4 * (l >> 4);
#pragma unroll
    for (int i = 0; i < 4; ++i) {
        const int grow = by * 128 + wr * 64 + i * 16 + rr;   // grow..grow+3 same s
        const int sI = grow >> 6, br = grow & 63;
#pragma unroll
        for (int j = 0; j < 4; ++j) {
            const int col = bx * 128 + wc * 64 + j * 16 + (l & 15);
            ushort4 o;
            o.x = f2bf(acc[i][j][0]); o.y = f2bf(acc[i][j][1]);
            o.z = f2bf(acc[i][j][2]); o.w = f2bf(acc[i][j][3]);
            *reinterpret_cast<ushort4*>(G2 + (size_t)sI * 262144 + (size_t)col * 64 + br) = o;
        }
    }
}

// ---------------- standalone G2 = X @ W_ih^T (chunk 0 only) ----------------
__global__ __launch_bounds__(256)
void gemm_gin(const unsigned short* __restrict__ X, const unsigned short* __restrict__ Wih,
              unsigned short* __restrict__ G2) {
    __shared__ __align__(16) unsigned short As[128][72];
    __shared__ __align__(16) unsigned short Bs[128][72];
    gemm_tile(X, Wih, G2, blockIdx.x & 31, blockIdx.x >> 5, As, Bs, threadIdx.x);
}

// ---------------- fused: recurrence (blocks 0-63) + next-chunk GEMM (64-191) ----
// Recurrence: 64 blocks x 512 threads. Block b owns hcols [16b,16b+16) -> 64
// gate-cols as 4 MFMA col-tiles (tile g = gate g). Waves (rh=w>>2, ch=w&3):
// rows rh*32..+31 (2 row-tiles), gate-tile ch, full K.
// Per step: stage FULL h (128KB) into LDS in 2 halves (2x64KB buffers,
// XOR-swizzled ^((row&15)<<4) on write AND read), MFMA from LDS (64/wave),
// f/g/o publish acc+G to red (12KB), i-wave does the cell (no shuffles).
// h via sc1 atomics/asm (IC-coherent); flag-array barrier (64 flags).
__global__ __launch_bounds__(512, 1)
void lstm_fused(const unsigned short* __restrict__ Gcur, unsigned short* __restrict__ Gnext,
                const unsigned short* __restrict__ Xnext, const unsigned short* __restrict__ Wih,
                const unsigned short* __restrict__ Whh,
                unsigned short* __restrict__ h0, unsigned short* __restrict__ h1,
                float* __restrict__ c_state, unsigned* __restrict__ flags, int t0, int do_gemm,
                float* __restrict__ out_h, float* __restrict__ out_c)
{
    __shared__ __align__(16) char smem[143360];   // 2x64K h halves + 12K red; gemm uses 72K

    const int tid = threadIdx.x;

    if (blockIdx.x >= 64) {
        // ---- GEMM half: two 128x128 tiles in lockstep per 512-thread block ----
        if (!do_gemm) return;
        const int sub = tid >> 8, stid = tid & 255;
        unsigned short (*As)[72] = reinterpret_cast<unsigned short(*)[72]>(smem + sub * 36864);
        unsigned short (*Bs)[72] = reinterpret_cast<unsigned short(*)[72]>(smem + sub * 36864 + 18432);
        const int base = (blockIdx.x - 64) * 8;
        for (int it = 0; it < 4; ++it) {
            const int tile = base + it * 2 + sub;
            gemm_tile(Xnext, Wih, Gnext, tile & 31, tile >> 5, As, Bs, stid);
        }
        return;
    }

    // ---- recurrence half ----
    char* const hS0 = smem;
    char* const hS1 = smem + 65536;
    float* const red = reinterpret_cast<float*>(smem + 131072);  // [rh][g-1][rt][64][4]

    const int b = blockIdx.x;
    const int w = tid >> 6, l = tid & 63;
    const int rh = w >> 2, ch = w & 3;
    const int koff = (l >> 4) * 8;
    const int hcol = b * 16 + (l & 15);
    const int gcol = ch * Hn + hcol;

    // W_hh fragments -> 128 VGPRs (once per launch); B-col = lane&15
    short8 breg[32];
    {
        const unsigned short* wr_ = Whh + ((size_t)(ch * Hn) + hcol) * Hn + koff;
#pragma unroll
        for (int j = 0; j < 32; ++j)
            breg[j] = *reinterpret_cast<const short8*>(wr_ + j * 32);
    }

    // c-state in registers (i-gate waves own the cell)
    float c_reg[2][4];
    if (ch == 0) {
#pragma unroll
        for (int rt = 0; rt < 2; ++rt) {
            const int rowbase = rh * 32 + rt * 16 + ((l >> 4) << 2);
#pragma unroll
            for (int r = 0; r < 4; ++r)
                c_reg[rt][r] = c_state[(rowbase + r) * Hn + hcol];
        }
    }

    // prologue: G2(s=0) for this wave's gate (4 rows per 8B load)
    ushort4 gp[2];
#pragma unroll
    for (int rt = 0; rt < 2; ++rt) {
        const int rowbase = rh * 32 + rt * 16 + ((l >> 4) << 2);
        gp[rt] = *reinterpret_cast<const ushort4*>(Gcur + (size_t)gcol * 64 + rowbase);
    }

    for (int s = 0; s < CHUNK; ++s) {
        const int t = t0 + s;
        const unsigned short* hin = (t & 1) ? h1 : h0;
        unsigned short* hout = (t & 1) ? h0 : h1;
        const char* hinB = (const char*)hin;

        f32x4 acc[2];
        acc[0] = (f32x4){0.f, 0.f, 0.f, 0.f};
        acc[1] = (f32x4){0.f, 0.f, 0.f, 0.f};

        u32x4 sb[8];
        // ---- stage half 0: unit u = tid + i*512; row=u>>6, kb=(u&63)*16 ----
#pragma unroll
        for (int i = 0; i < 8; ++i) {
            const int u = tid + i * 512;
            LDHA(sb[i], hinB + (u >> 6) * 2048 + ((u & 63) * 16));
        }
        VMW0;
#pragma unroll
        for (int i = 0; i < 8; ++i) {
            const int u = tid + i * 512;
            const int row = u >> 6, kb = (u & 63) * 16;
            *reinterpret_cast<u32x4*>(hS0 + ((row * 1024 + kb) ^ ((row & 15) << 4))) = sb[i];
        }
        __syncthreads();

        // ---- issue stage half 1 (flies under MFMA half 0) ----
#pragma unroll
        for (int i = 0; i < 8; ++i) {
            const int u = tid + i * 512;
            LDHA(sb[i], hinB + (u >> 6) * 2048 + 1024 + ((u & 63) * 16));
        }

        // ---- MFMA half 0 ----
#pragma unroll
        for (int jj = 0; jj < 16; ++jj) {
#pragma unroll
            for (int rt = 0; rt < 2; ++rt) {
                const int row = rh * 32 + rt * 16 + (l & 15);
                const int kb = jj * 64 + (l >> 4) * 16;
                short8 af = *reinterpret_cast<const short8*>(
                    hS0 + ((row * 1024 + kb) ^ ((row & 15) << 4)));
                acc[rt] = __builtin_amdgcn_mfma_f32_16x16x32_bf16(af, breg[jj], acc[rt], 0, 0, 0);
            }
        }

        VMW0;   // half-1 loads landed (issued before MFMA half 0)
#pragma unroll
        for (int i = 0; i < 8; ++i) {
            const int u = tid + i * 512;
            const int row = u >> 6, kb = (u & 63) * 16;
            *reinterpret_cast<u32x4*>(hS1 + ((row * 1024 + kb) ^ ((row & 15) << 4))) = sb[i];
        }
        __syncthreads();

        // ---- MFMA half 1 ----
#pragma unroll
        for (int jj = 0; jj < 16; ++jj) {
#pragma unroll
            for (int rt = 0; rt < 2; ++rt) {
                const int row = rh * 32 + rt * 16 + (l & 15);
                const int kb = jj * 64 + (l >> 4) * 16;
                short8 af = *reinterpret_cast<const short8*>(
                    hS1 + ((row * 1024 + kb) ^ ((row & 15) << 4)));
                acc[rt] = __builtin_amdgcn_mfma_f32_16x16x32_bf16(af, breg[16 + jj], acc[rt], 0, 0, 0);
            }
        }

        // ---- f/g/o waves: add G, publish to red ----
        if (ch != 0) {
#pragma unroll
            for (int rt = 0; rt < 2; ++rt) {
                f32x4 v = acc[rt];
                v[0] += bf2f(gp[rt].x); v[1] += bf2f(gp[rt].y);
                v[2] += bf2f(gp[rt].z); v[3] += bf2f(gp[rt].w);
                *reinterpret_cast<f32x4*>(red + (((rh * 3 + (ch - 1)) * 2 + rt) * 64 + l) * 4) = v;
            }
        }
        __syncthreads();

        // ---- i-gate waves: cell update (all 4 gates lane-local, no shuffles) ----
        if (ch == 0) {
#pragma unroll
            for (int rt = 0; rt < 2; ++rt) {
                const int rowbase = rh * 32 + rt * 16 + ((l >> 4) << 2);
                f32x4 fv4 = *reinterpret_cast<f32x4*>(red + (((rh * 3 + 0) * 2 + rt) * 64 + l) * 4);
                f32x4 gv4 = *reinterpret_cast<f32x4*>(red + (((rh * 3 + 1) * 2 + rt) * 64 + l) * 4);
                f32x4 ov4 = *reinterpret_cast<f32x4*>(red + (((rh * 3 + 2) * 2 + rt) * 64 + l) * 4);
                const unsigned short gpi[4] = {gp[rt].x, gp[rt].y, gp[rt].z, gp[rt].w};
#pragma unroll
                for (int r = 0; r < 4; ++r) {
                    float iv = acc[rt][r] + bf2f(gpi[r]);
                    float cn = sigm(fv4[r]) * c_reg[rt][r] + sigm(iv) * tanh_fast(gv4[r]);
                    float hn = sigm(ov4[r]) * tanh_fast(cn);
                    c_reg[rt][r] = cn;
                    unsigned hb = f2bf(hn);
                    unsigned partner = (unsigned)__shfl_xor((int)hb, 1);
                    if (!(l & 1)) {
                        unsigned val = (hb & 0xFFFFu) | (partner << 16);
                        __hip_atomic_store(
                            (unsigned*)(hout + (size_t)(rowbase + r) * Hn + hcol),
                            val, __ATOMIC_RELAXED, AGENT);
                    }
                    if (t == Tn - 1) {
                        out_h[(rowbase + r) * Hn + hcol] = hn;
                        out_c[(rowbase + r) * Hn + hcol] = cn;
                    }
                }
            }
        }

        // ---- drain h-stores; arrive; prefetch G2(s+1); poll 64 flags ----
        asm volatile("s_waitcnt vmcnt(0)" ::: "memory");
        __syncthreads();
        if (tid == 0)
            __hip_atomic_store(&flags[b * 32], (unsigned)(t + 1), __ATOMIC_RELAXED, AGENT);
        if (s + 1 < CHUNK) {
            const unsigned short* G1 = Gcur + (size_t)(s + 1) * 262144;
#pragma unroll
            for (int rt = 0; rt < 2; ++rt) {
                const int rowbase = rh * 32 + rt * 16 + ((l >> 4) << 2);
                gp[rt] = *reinterpret_cast<const ushort4*>(G1 + (size_t)gcol * 64 + rowbase);
            }
        }
        {
            const unsigned target = (unsigned)(t + 1);
            const int pf = (tid & 63) * 32;
            int guard = 0;
            while (__hip_atomic_load(&flags[pf], __ATOMIC_RELAXED, AGENT) < target &&
                   guard < (1 << 16)) {
                __builtin_amdgcn_s_sleep(1);
                ++guard;
            }
        }
        __syncthreads();
    }

    if (ch == 0) {
#pragma unroll
        for (int rt = 0; rt < 2; ++rt) {
            const int rowbase = rh * 32 + rt * 16 + ((l >> 4) << 2);
#pragma unroll
            for (int r = 0; r < 4; ++r)
                c_state[(rowbase + r) * Hn + hcol] = c_reg[rt][r];
        }
    }
}

// ---------------- classifier: logits[64,V] = h @ W_cls^T + b ----------------
__global__ __launch_bounds__(256)
void classifier(const unsigned short* __restrict__ h,
                const float* __restrict__ Wcls, const float* __restrict__ bcls,
                float* __restrict__ logits)
{
    __shared__ __align__(16) unsigned short Al[64][72];
    __shared__ __align__(16) unsigned short Bl[64][72];

    const int tid = threadIdx.x;
    const int v0 = blockIdx.x * 64;
    const int w = tid >> 6, l = tid & 63;
    const int lrow = tid >> 2, q = tid & 3;
    const int v = v0 + lrow;

    const unsigned short* hrow = h + lrow * Hn;
    const float* wrow = Wcls + (size_t)v * Hn;

    f32x4 acc[4];
#pragma unroll
    for (int ct = 0; ct < 4; ++ct) acc[ct] = (f32x4){0.f, 0.f, 0.f, 0.f};

    const int arow = w * 16 + (l & 15);
    const int koff = (l >> 4) * 8;

    for (int ch = 0; ch < 16; ++ch) {
        const int k0 = ch * 64;
        __syncthreads();
#pragma unroll
        for (int i2 = 0; i2 < 4; ++i2) {
            const int k = q * 4 + i2 * 16;
            *reinterpret_cast<ushort4*>(&Al[lrow][k]) =
                *reinterpret_cast<const ushort4*>(hrow + k0 + k);
            if (v < Vn) {
                float4 x = *reinterpret_cast<const float4*>(wrow + k0 + k);
                Bl[lrow][k + 0] = f2bf(x.x); Bl[lrow][k + 1] = f2bf(x.y);
                Bl[lrow][k + 2] = f2bf(x.z); Bl[lrow][k + 3] = f2bf(x.w);
            } else {
                ushort4 z; z.x = z.y = z.z = z.w = 0;
                *reinterpret_cast<ushort4*>(&Bl[lrow][k]) = z;
            }
        }
        __syncthreads();

        short8 a0 = *reinterpret_cast<const short8*>(&Al[arow][koff]);
        short8 a1 = *reinterpret_cast<const short8*>(&Al[arow][32 + koff]);
#pragma unroll
        for (int ct = 0; ct < 4; ++ct) {
            const int bcol = ct * 16 + (l & 15);
            short8 b0 = *reinterpret_cast<const short8*>(&Bl[bcol][koff]);
            short8 b1 = *reinterpret_cast<const short8*>(&Bl[bcol][32 + koff]);
            acc[ct] = __builtin_amdgcn_mfma_f32_16x16x32_bf16(a0, b0, acc[ct], 0, 0, 0);
            acc[ct] = __builtin_amdgcn_mfma_f32_16x16x32_bf16(a1, b1, acc[ct], 0, 0, 0);
        }
    }

    const int rr0 = w * 16 + (l >> 4) * 4;
#pragma unroll
    for (int ct = 0; ct < 4; ++ct) {
        const int vv = v0 + ct * 16 + (l & 15);
        if (vv < Vn) {
            float bb = bcls[vv];
#pragma unroll
            for (int r = 0; r < 4; ++r)
                logits[(size_t)(rr0 + r) * Vn + vv] = acc[ct][r] + bb;
        }
    }
}

extern "C" void kernel_launch(void* const* d_in, const int* in_sizes, int n_in,
                              void* d_out, int out_size, void* d_ws, size_t ws_size,
                              hipStream_t stream)
{
    const int*   tokens = (const int*)d_in[0];
    const float* emb    = (const float*)d_in[1];
    const float* W_ih   = (const float*)d_in[2];
    const float* W_hh   = (const float*)d_in[3];
    const float* W_cls  = (const float*)d_in[4];
    const float* b_cls  = (const float*)d_in[5];
    float* out = (float*)d_out;

    // ws layout (~89 MB):
    // [h0 128K][h1 128K][c 256K][flags 16K][Wih 8M][Whh 8M][X 8M][G2_0 32M][G2_1 32M]
    char* ws = (char*)d_ws;
    unsigned short* hbuf0 = (unsigned short*)ws;
    unsigned short* hbuf1 = (unsigned short*)(ws + 131072);
    float*          cst   = (float*)(ws + 262144);
    unsigned*       flags = (unsigned*)(ws + 524288);
    unsigned short* Wih_b = (unsigned short*)(ws + 540672);
    unsigned short* Whh_b = (unsigned short*)(ws + 540672 + 8388608);
    unsigned short* Xb    = (unsigned short*)(ws + 540672 + 2 * 8388608);
    unsigned short* Gb0   = (unsigned short*)(ws + 540672 + 3 * 8388608);
    unsigned short* Gb1   = (unsigned short*)(ws + 540672 + 3 * 8388608 + 33554432);

    // zero h(0), c(0), flags each call
    hipMemsetAsync(ws, 0, 540672, stream);

    const int n4 = (4 * Hn * En) / 4;
    cvt_f32_bf16<<<n4 / 256, 256, 0, stream>>>(W_ih, Wih_b, n4);
    cvt_f32_bf16<<<n4 / 256, 256, 0, stream>>>(W_hh, Whh_b, n4);

    float* out_h = out + (size_t)Bn * Vn;
    float* out_c = out_h + Bn * Hn;

    // chunk 0: gather + standalone gemm (full chip)
    gather_x<<<CHUNK * Bn, 256, 0, stream>>>(tokens, emb, Xb, 0);
    gemm_gin<<<32 * 32, 256, 0, stream>>>(Xb, Wih_b, Gb0);

    unsigned short* Gbuf[2] = {Gb0, Gb1};
    for (int c = 0; c < NCHUNK; ++c) {
        const int do_gemm = (c + 1 < NCHUNK) ? 1 : 0;
        if (do_gemm)
            gather_x<<<CHUNK * Bn, 256, 0, stream>>>(tokens, emb, Xb, (c + 1) * CHUNK);
        lstm_fused<<<192, 512, 0, stream>>>(Gbuf[c & 1], Gbuf[(c + 1) & 1], Xb,
                                            Wih_b, Whh_b, hbuf0, hbuf1,
                                            cst, flags, c * CHUNK, do_gemm,
                                            out_h, out_c);
    }

    classifier<<<(Vn + 63) / 64, 256, 0, stream>>>(hbuf0, W_cls, b_cls, out);
}

// Round 11
// 4258.133 us; speedup vs baseline: 1.0832x; 1.0832x over previous
//
#include <hip/hip_runtime.h>

// Problem dims (fixed)
#define Bn 64
#define Tn 512
#define En 1024
#define Hn 1024
#define Vn 50257
#define CHUNK 64
#define NCHUNK (Tn / CHUNK)
#define AGENT __HIP_MEMORY_SCOPE_AGENT

typedef __attribute__((ext_vector_type(8))) short short8;
typedef __attribute__((ext_vector_type(4))) float f32x4;
typedef __attribute__((ext_vector_type(4))) unsigned int u32x4;

__device__ __forceinline__ unsigned short f2bf(float f) {
    union { float f; unsigned u; } x; x.f = f;
    unsigned r = x.u + 0x7FFFu + ((x.u >> 16) & 1u);   // RNE; values are tame
    return (unsigned short)(r >> 16);
}
__device__ __forceinline__ float bf2f(unsigned short u) {
    union { unsigned u; float f; } x; x.u = ((unsigned)u) << 16; return x.f;
}
__device__ __forceinline__ float sigm(float x) { return 1.0f / (1.0f + __expf(-x)); }
__device__ __forceinline__ float tanh_fast(float x) {
    float e = __expf(2.0f * x);
    return (e - 1.0f) / (e + 1.0f);
}

// 16B IC-coherent load (bypasses L1/L2 -> coherent at Infinity Cache)
#define LDH(dst, base, IMM)                                                  \
    asm volatile("global_load_dwordx4 %0, %1, off offset:" #IMM " sc0 sc1"   \
                 : "=v"(dst) : "v"(base) : "memory")
// counted wait + scheduler fence (rule #18)
#define VMW(N) do { asm volatile("s_waitcnt vmcnt(" #N ")" ::: "memory");    \
                    __builtin_amdgcn_sched_barrier(0); } while (0)
// issue one group of 8 16B h-loads (2 row-tiles x 4 consecutive j)
#define ISSUE_GRP(buf, O0, O1, O2, O3)                                       \
    do {                                                                     \
        LDH((buf)[0], ap0, O0); LDH((buf)[1], ap0, O1);                      \
        LDH((buf)[2], ap0, O2); LDH((buf)[3], ap0, O3);                      \
        LDH((buf)[4], ap1, O0); LDH((buf)[5], ap1, O1);                      \
        LDH((buf)[6], ap1, O2); LDH((buf)[7], ap1, O3);                      \
    } while (0)
// consume 8 fragments against breg[ct][jb..jb+3]
#define MFMA_GRP(buf, jb)                                                    \
    do {                                                                     \
        _Pragma("unroll")                                                    \
        for (int jj = 0; jj < 4; ++jj) {                                     \
            union { u32x4 u; short8 s; } f0, f1;                             \
            f0.u = (buf)[jj]; f1.u = (buf)[4 + jj];                          \
            acc[0][0] = __builtin_amdgcn_mfma_f32_16x16x32_bf16(f0.s, breg[0][(jb) + jj], acc[0][0], 0, 0, 0); \
            acc[0][1] = __builtin_amdgcn_mfma_f32_16x16x32_bf16(f0.s, breg[1][(jb) + jj], acc[0][1], 0, 0, 0); \
            acc[1][0] = __builtin_amdgcn_mfma_f32_16x16x32_bf16(f1.s, breg[0][(jb) + jj], acc[1][0], 0, 0, 0); \
            acc[1][1] = __builtin_amdgcn_mfma_f32_16x16x32_bf16(f1.s, breg[1][(jb) + jj], acc[1][1], 0, 0, 0); \
        }                                                                    \
    } while (0)

// ---------------- fp32 -> bf16 weight convert ----------------
__global__ __launch_bounds__(256)
void cvt_f32_bf16(const float* __restrict__ src, unsigned short* __restrict__ dst, int n4) {
    int i = blockIdx.x * 256 + threadIdx.x;
    if (i < n4) {
        float4 v = reinterpret_cast<const float4*>(src)[i];
        ushort4 o;
        o.x = f2bf(v.x); o.y = f2bf(v.y); o.z = f2bf(v.z); o.w = f2bf(v.w);
        reinterpret_cast<ushort4*>(dst)[i] = o;
    }
}

// ---------------- embedding gather for one 64-step chunk ----------------
__global__ __launch_bounds__(256)
void gather_x(const int* __restrict__ tokens, const float* __restrict__ emb,
              unsigned short* __restrict__ X, int t0) {
    const int r = blockIdx.x;
    const int trel = r >> 6, b = r & 63;
    const int tok = tokens[b * Tn + t0 + trel];
    const float* src = emb + (size_t)tok * En;
    const int k = threadIdx.x * 4;
    float4 v = *reinterpret_cast<const float4*>(src + k);
    ushort4 o;
    o.x = f2bf(v.x); o.y = f2bf(v.y); o.z = f2bf(v.z); o.w = f2bf(v.w);
    *reinterpret_cast<ushort4*>(X + (size_t)r * En + k) = o;
}

// ---- shared gemm tile body: one 128x128 tile of X @ Wih^T (bf16 out) ----
__device__ __forceinline__ void gemm_tile(
    const unsigned short* __restrict__ X, const unsigned short* __restrict__ Wih,
    unsigned short* __restrict__ G, int bx, int by,
    unsigned short (*As)[72], unsigned short (*Bs)[72], int tid)
{
    const int w = tid >> 6, l = tid & 63;
    const int wr = w >> 1, wc = w & 1;
    const int koff = (l >> 4) * 8;

    f32x4 acc[4][4];
#pragma unroll
    for (int i = 0; i < 4; ++i)
#pragma unroll
        for (int j = 0; j < 4; ++j) acc[i][j] = (f32x4){0.f, 0.f, 0.f, 0.f};

    for (int kk = 0; kk < En / 64; ++kk) {
        __syncthreads();
#pragma unroll
        for (int j = 0; j < 4; ++j) {
            const int u = tid * 4 + j;
            const int row = u >> 3, ku = (u & 7) * 8;
            *reinterpret_cast<short8*>(&As[row][ku]) =
                *reinterpret_cast<const short8*>(X + (size_t)(by * 128 + row) * En + kk * 64 + ku);
            *reinterpret_cast<short8*>(&Bs[row][ku]) =
                *reinterpret_cast<const short8*>(Wih + (size_t)(bx * 128 + row) * En + kk * 64 + ku);
        }
        __syncthreads();

#pragma unroll
        for (int kc = 0; kc < 2; ++kc) {
            const int k0 = kc * 32 + koff;
            short8 af[4], bf[4];
#pragma unroll
            for (int i = 0; i < 4; ++i)
                af[i] = *reinterpret_cast<const short8*>(&As[wr * 64 + i * 16 + (l & 15)][k0]);
#pragma unroll
            for (int j = 0; j < 4; ++j)
                bf[j] = *reinterpret_cast<const short8*>(&Bs[wc * 64 + j * 16 + (l & 15)][k0]);
#pragma unroll
            for (int i = 0; i < 4; ++i)
#pragma unroll
                for (int j = 0; j < 4; ++j)
                    acc[i][j] = __builtin_amdgcn_mfma_f32_16x16x32_bf16(af[i], bf[j], acc[i][j], 0, 0, 0);
        }
    }

    const int rr = 4 * (l >> 4);
#pragma unroll
    for (int i = 0; i < 4; ++i) {
        const int row = by * 128 + wr * 64 + i * 16 + rr;
#pragma unroll
        for (int j = 0; j < 4; ++j) {
            const int col = bx * 128 + wc * 64 + j * 16 + (l & 15);
#pragma unroll
            for (int r = 0; r < 4; ++r)
                G[(size_t)(row + r) * 4096 + col] = f2bf(acc[i][j][r]);
        }
    }
}

// ---------------- standalone G = X @ W_ih^T (chunk 0 only), bf16 out ----------------
__global__ __launch_bounds__(256)
void gemm_gin(const unsigned short* __restrict__ X, const unsigned short* __restrict__ Wih,
              unsigned short* __restrict__ G) {
    __shared__ __align__(16) unsigned short As[128][72];
    __shared__ __align__(16) unsigned short Bs[128][72];
    gemm_tile(X, Wih, G, blockIdx.x & 31, blockIdx.x >> 5, As, Bs, threadIdx.x);
}

// ---------------- fused: recurrence (blocks 0-127) + next-chunk GEMM (128-255) ----
// SELF-TIMED DATAFLOW SYNC (no global barrier): wave kh only consumes h-cols
// [512kh,512kh+512) = producers [64kh,64kh+64). At the top of each step the
// wave polls those 64 flags (one per lane; exec-mask holds the wave). Safety:
// producer q can only overwrite h(t) (computing h(t+2)) after seeing all
// flags >= t+1, which are set only after each block finished READING h(t).
// The poll's flag load forces vmcnt(0) (in-order counter) -> it drains the
// G-prefetch queue, so the counted VMW(24/16/8/0) window is exact for both kh.
__global__ __launch_bounds__(256, 1)
void lstm_fused(const unsigned short* __restrict__ Gcur, unsigned short* __restrict__ Gnext,
                const unsigned short* __restrict__ Xnext, const unsigned short* __restrict__ Wih,
                const unsigned short* __restrict__ Whh,
                unsigned short* __restrict__ h0, unsigned short* __restrict__ h1,
                float* __restrict__ c_state, unsigned* __restrict__ flags, int t0, int do_gemm,
                float* __restrict__ out_h, float* __restrict__ out_c)
{
    __shared__ __align__(16) char smem[2 * 128 * 72 * 2];   // 36 KB (gemm As/Bs; recurrence red 16 KB)

    const int tid = threadIdx.x;

    if (blockIdx.x >= 128) {
        // ---- GEMM half: 8 tiles of G(next chunk); no sync participation ----
        if (!do_gemm) return;
        unsigned short (*As)[72] = reinterpret_cast<unsigned short(*)[72]>(smem);
        unsigned short (*Bs)[72] = reinterpret_cast<unsigned short(*)[72]>(smem + 128 * 72 * 2);
        const int base = (blockIdx.x - 128) * 8;
        for (int tt = 0; tt < 8; ++tt) {
            const int tile = base + tt;
            gemm_tile(Xnext, Wih, Gnext, tile & 31, tile >> 5, As, Bs, tid);
        }
        return;
    }

    // ---- recurrence half ----
    typedef float RedT[2][2][64][4];                 // [rt][ct][lane][r]
    RedT* red = reinterpret_cast<RedT*>(smem);       // red[rh][...], 16 KB

    const int b = blockIdx.x;
    const int w = tid >> 6, l = tid & 63;
    const int kh = w & 1, rh = w >> 1;
    const int koff = (l >> 4) * 8;
    const int lc = l & 15;
    const int hcol = b * 8 + (l & 7);

    // W_hh fragments -> registers (once per launch)
    short8 breg[2][16];
#pragma unroll
    for (int ct = 0; ct < 2; ++ct) {
        const int gate = ct * 2 + (lc >> 3);
        const unsigned short* wrow = Whh + ((size_t)gate * Hn + (b * 8 + (lc & 7))) * Hn;
#pragma unroll
        for (int j = 0; j < 16; ++j)
            breg[ct][j] = *reinterpret_cast<const short8*>(wrow + (kh * 16 + j) * 32 + koff);
    }

    // c-state in registers (kh==0 waves own the cell update)
    float c_reg[2][4];
    if (kh == 0) {
#pragma unroll
        for (int rt = 0; rt < 2; ++rt)
#pragma unroll
            for (int r = 0; r < 4; ++r)
                c_reg[rt][r] = c_state[(rh * 32 + rt * 16 + ((l >> 4) << 2) + r) * Hn + hcol];
    }

    const int sg = lc >> 3;
    const int gc0 = sg * Hn + hcol;          // i (sg=0) / f (sg=1)
    const int gc1 = (2 + sg) * Hn + hcol;    // g / o

    // prologue: prefetch G(s=0), bf16 (drained by the first poll)
    unsigned short gp0[2][4], gp1[2][4];
    if (kh == 0) {
#pragma unroll
        for (int rt = 0; rt < 2; ++rt) {
            const int rowbase = rh * 32 + rt * 16 + ((l >> 4) << 2);
#pragma unroll
            for (int r = 0; r < 4; ++r) {
                gp0[rt][r] = Gcur[(size_t)(rowbase + r) * 4096 + gc0];
                gp1[rt][r] = Gcur[(size_t)(rowbase + r) * 4096 + gc1];
            }
        }
    }

    // this wave's producer flag (one per lane): producers [64kh, 64kh+64)
    const unsigned* myflag = &flags[(kh * 64 + l) * 32];

    for (int s = 0; s < CHUNK; ++s) {
        const int t = t0 + s;
        const unsigned short* hin = (t & 1) ? h1 : h0;
        unsigned short* hout = (t & 1) ? h0 : h1;

        // ---- per-wave dataflow sync: h(t) slices of this K-half ready? ----
        {
            const unsigned target = (unsigned)t;
            int guard = 0;
            while (__hip_atomic_load(myflag, __ATOMIC_RELAXED, AGENT) < target &&
                   guard < (1 << 16)) {
                __builtin_amdgcn_s_sleep(1);
                ++guard;
            }
        }
        __builtin_amdgcn_sched_barrier(0);

        const unsigned short* ap0 =
            hin + (size_t)(rh * 32 + (l & 15)) * Hn + kh * 512 + koff;
        const unsigned short* ap1 =
            hin + (size_t)(rh * 32 + 16 + (l & 15)) * Hn + kh * 512 + koff;

        f32x4 acc[2][2];
        acc[0][0] = acc[0][1] = acc[1][0] = acc[1][1] = (f32x4){0.f, 0.f, 0.f, 0.f};

        u32x4 bufA[8], bufB[8], bufC[8], bufD[8];
        ISSUE_GRP(bufA, 0,   64,  128, 192);   // j = 0..3
        ISSUE_GRP(bufB, 256, 320, 384, 448);   // j = 4..7
        ISSUE_GRP(bufC, 512, 576, 640, 704);   // j = 8..11
        ISSUE_GRP(bufD, 768, 832, 896, 960);   // j = 12..15

        VMW(24); MFMA_GRP(bufA, 0);
        VMW(16); MFMA_GRP(bufB, 4);
        VMW(8);  MFMA_GRP(bufC, 8);
        VMW(0);  MFMA_GRP(bufD, 12);

        // K-split reduction via LDS
        if (kh == 1) {
#pragma unroll
            for (int rt = 0; rt < 2; ++rt)
#pragma unroll
                for (int ct = 0; ct < 2; ++ct)
                    *reinterpret_cast<f32x4*>(&red[rh][rt][ct][l][0]) = acc[rt][ct];
        }
        __syncthreads();

        if (kh == 0) {
#pragma unroll
            for (int rt = 0; rt < 2; ++rt) {
                const int rowbase = rh * 32 + rt * 16 + ((l >> 4) << 2);
                f32x4 a0 = acc[rt][0] + *reinterpret_cast<f32x4*>(&red[rh][rt][0][l][0]);
                f32x4 a1 = acc[rt][1] + *reinterpret_cast<f32x4*>(&red[rh][rt][1][l][0]);
#pragma unroll
                for (int r = 0; r < 4; ++r) {
                    float v0 = a0[r] + bf2f(gp0[rt][r]);
                    float v1 = a1[r] + bf2f(gp1[rt][r]);
                    float p0 = __shfl_xor(v0, 8);
                    float p1 = __shfl_xor(v1, 8);
                    float iv = (l & 8) ? p0 : v0;
                    float fv = (l & 8) ? v0 : p0;
                    float gv = (l & 8) ? p1 : v1;
                    float ov = (l & 8) ? v1 : p1;
                    float cn = sigm(fv) * c_reg[rt][r] + sigm(iv) * tanh_fast(gv);
                    float hn = sigm(ov) * tanh_fast(cn);
                    c_reg[rt][r] = cn;
                    unsigned hb = f2bf(hn);
                    unsigned partner = (unsigned)__shfl_xor((int)hb, 1);
                    if (!(l & 8) && !(l & 1)) {
                        unsigned val = (hb & 0xFFFFu) | (partner << 16);
                        __hip_atomic_store(
                            (unsigned*)(hout + (size_t)(rowbase + r) * Hn + hcol),
                            val, __ATOMIC_RELAXED, AGENT);
                    }
                    if (t == Tn - 1 && !(l & 8)) {
                        out_h[(rowbase + r) * Hn + hcol] = hn;
                        out_c[(rowbase + r) * Hn + hcol] = cn;
                    }
                }
            }
        }

        // per-wave drain of own h-stores, block-wide order, then arrive
        asm volatile("s_waitcnt vmcnt(0)" ::: "memory");
        __syncthreads();
        if (tid == 0)
            __hip_atomic_store(&flags[b * 32], (unsigned)(t + 1), __ATOMIC_RELAXED, AGENT);

        // prefetch G(s+1): sits in queue, drained by next step's poll
        if (kh == 0 && s + 1 < CHUNK) {
            const unsigned short* Gt = Gcur + (size_t)(s + 1) * Bn * 4096;
#pragma unroll
            for (int rt = 0; rt < 2; ++rt) {
                const int rowbase = rh * 32 + rt * 16 + ((l >> 4) << 2);
#pragma unroll
                for (int r = 0; r < 4; ++r) {
                    gp0[rt][r] = Gt[(size_t)(rowbase + r) * 4096 + gc0];
                    gp1[rt][r] = Gt[(size_t)(rowbase + r) * 4096 + gc1];
                }
            }
        }
    }

    if (kh == 0 && !(l & 8)) {
#pragma unroll
        for (int rt = 0; rt < 2; ++rt)
#pragma unroll
            for (int r = 0; r < 4; ++r)
                c_state[(rh * 32 + rt * 16 + ((l >> 4) << 2) + r) * Hn + hcol] = c_reg[rt][r];
    }
}

// ---------------- classifier: logits[64,V] = h @ W_cls^T + b ----------------
__global__ __launch_bounds__(256)
void classifier(const unsigned short* __restrict__ h,
                const float* __restrict__ Wcls, const float* __restrict__ bcls,
                float* __restrict__ logits)
{
    __shared__ __align__(16) unsigned short Al[64][72];
    __shared__ __align__(16) unsigned short Bl[64][72];

    const int tid = threadIdx.x;
    const int v0 = blockIdx.x * 64;
    const int w = tid >> 6, l = tid & 63;
    const int lrow = tid >> 2, q = tid & 3;
    const int v = v0 + lrow;

    const unsigned short* hrow = h + lrow * Hn;
    const float* wrow = Wcls + (size_t)v * Hn;

    f32x4 acc[4];
#pragma unroll
    for (int ct = 0; ct < 4; ++ct) acc[ct] = (f32x4){0.f, 0.f, 0.f, 0.f};

    const int arow = w * 16 + (l & 15);
    const int koff = (l >> 4) * 8;

    for (int ch = 0; ch < 16; ++ch) {
        const int k0 = ch * 64;
        __syncthreads();
#pragma unroll
        for (int i2 = 0; i2 < 4; ++i2) {
            const int k = q * 4 + i2 * 16;
            *reinterpret_cast<ushort4*>(&Al[lrow][k]) =
                *reinterpret_cast<const ushort4*>(hrow + k0 + k);
            if (v < Vn) {
                float4 x = *reinterpret_cast<const float4*>(wrow + k0 + k);
                Bl[lrow][k + 0] = f2bf(x.x); Bl[lrow][k + 1] = f2bf(x.y);
                Bl[lrow][k + 2] = f2bf(x.z); Bl[lrow][k + 3] = f2bf(x.w);
            } else {
                ushort4 z; z.x = z.y = z.z = z.w = 0;
                *reinterpret_cast<ushort4*>(&Bl[lrow][k]) = z;
            }
        }
        __syncthreads();

        short8 a0 = *reinterpret_cast<const short8*>(&Al[arow][koff]);
        short8 a1 = *reinterpret_cast<const short8*>(&Al[arow][32 + koff]);
#pragma unroll
        for (int ct = 0; ct < 4; ++ct) {
            const int bcol = ct * 16 + (l & 15);
            short8 b0 = *reinterpret_cast<const short8*>(&Bl[bcol][koff]);
            short8 b1 = *reinterpret_cast<const short8*>(&Bl[bcol][32 + koff]);
            acc[ct] = __builtin_amdgcn_mfma_f32_16x16x32_bf16(a0, b0, acc[ct], 0, 0, 0);
            acc[ct] = __builtin_amdgcn_mfma_f32_16x16x32_bf16(a1, b1, acc[ct], 0, 0, 0);
        }
    }

    const int rr0 = w * 16 + (l >> 4) * 4;
#pragma unroll
    for (int ct = 0; ct < 4; ++ct) {
        const int vv = v0 + ct * 16 + (l & 15);
        if (vv < Vn) {
            float bb = bcls[vv];
#pragma unroll
            for (int r = 0; r < 4; ++r)
                logits[(size_t)(rr0 + r) * Vn + vv] = acc[ct][r] + bb;
        }
    }
}

extern "C" void kernel_launch(void* const* d_in, const int* in_sizes, int n_in,
                              void* d_out, int out_size, void* d_ws, size_t ws_size,
                              hipStream_t stream)
{
    const int*   tokens = (const int*)d_in[0];
    const float* emb    = (const float*)d_in[1];
    const float* W_ih   = (const float*)d_in[2];
    const float* W_hh   = (const float*)d_in[3];
    const float* W_cls  = (const float*)d_in[4];
    const float* b_cls  = (const float*)d_in[5];
    float* out = (float*)d_out;

    // ws layout (~89 MB):
    // [h0 128K][h1 128K][c 256K][flags 16K][Wih 8M][Whh 8M][X 8M][G0 32M][G1 32M]
    char* ws = (char*)d_ws;
    unsigned short* hbuf0 = (unsigned short*)ws;
    unsigned short* hbuf1 = (unsigned short*)(ws + 131072);
    float*          cst   = (float*)(ws + 262144);
    unsigned*       flags = (unsigned*)(ws + 524288);
    unsigned short* Wih_b = (unsigned short*)(ws + 540672);
    unsigned short* Whh_b = (unsigned short*)(ws + 540672 + 8388608);
    unsigned short* Xb    = (unsigned short*)(ws + 540672 + 2 * 8388608);
    unsigned short* Gb0   = (unsigned short*)(ws + 540672 + 3 * 8388608);
    unsigned short* Gb1   = (unsigned short*)(ws + 540672 + 3 * 8388608 + 33554432);

    // zero h(0), c(0), flags each call
    hipMemsetAsync(ws, 0, 540672, stream);

    const int n4 = (4 * Hn * En) / 4;
    cvt_f32_bf16<<<n4 / 256, 256, 0, stream>>>(W_ih, Wih_b, n4);
    cvt_f32_bf16<<<n4 / 256, 256, 0, stream>>>(W_hh, Whh_b, n4);

    float* out_h = out + (size_t)Bn * Vn;
    float* out_c = out_h + Bn * Hn;

    // chunk 0: gather + standalone gemm
    gather_x<<<CHUNK * Bn, 256, 0, stream>>>(tokens, emb, Xb, 0);
    gemm_gin<<<32 * 32, 256, 0, stream>>>(Xb, Wih_b, Gb0);

    unsigned short* Gbuf[2] = {Gb0, Gb1};
    for (int c = 0; c < NCHUNK; ++c) {
        const int do_gemm = (c + 1 < NCHUNK) ? 1 : 0;
        if (do_gemm)
            gather_x<<<CHUNK * Bn, 256, 0, stream>>>(tokens, emb, Xb, (c + 1) * CHUNK);
        lstm_fused<<<256, 256, 0, stream>>>(Gbuf[c & 1], Gbuf[(c + 1) & 1], Xb,
                                            Wih_b, Whh_b, hbuf0, hbuf1,
                                            cst, flags, c * CHUNK, do_gemm,
                                            out_h, out_c);
    }

    classifier<<<(Vn + 63) / 64, 256, 0, stream>>>(hbuf0, W_cls, b_cls, out);
}